// Round 18
// baseline (1347.667 us; speedup 1.0000x reference)
//
#include <hip/hip_runtime.h>
#include <stdint.h>

#define T_STEPS 256
#define EMBD 10
#define NKIT 9          // K = 288 = 9*32 (256 h + 10 x + 1 bias + pad)
#define NBLK_K1 (64 * NKIT)
#define NBLK 256        // main grid: 4 hcol-quarters x 64 batch-groups

typedef __attribute__((ext_vector_type(8))) short bf16x8;
typedef __attribute__((ext_vector_type(4))) float f32x4;
typedef __attribute__((ext_vector_type(4))) int   i32x4;

__device__ __forceinline__ unsigned short f2bf(float f) {
    union { float f; unsigned int u; } v; v.f = f;
    unsigned int u = v.u;
    unsigned int r = (u + 0x7FFFu + ((u >> 16) & 1u)) >> 16;  // RNE
    return (unsigned short)r;
}
__device__ __forceinline__ float sig_fast(float x) {
    return __builtin_amdgcn_rcpf(1.0f + __builtin_amdgcn_exp2f(-1.4426950408889634f * x));
}
__device__ __forceinline__ float tanh_fast(float x) {
    return 1.0f - 2.0f * __builtin_amdgcn_rcpf(__builtin_amdgcn_exp2f(2.8853900817779268f * x) + 1.0f);
}
__device__ __forceinline__ f32x4 mfma_v(i32x4 a, i32x4 b, f32x4 c) {
    return __builtin_amdgcn_mfma_f32_16x16x32_bf16(
        __builtin_bit_cast(bf16x8, a), __builtin_bit_cast(bf16x8, b), c, 0, 0, 0);
}

// ---------------------------------------------------------------------------
// K1: swizzled bf16 weights [kit][ntile][lane] x 16B + zero the 2 MB hxc
// (seq words must start != any expected step; zero works, expected >= 1).
// ---------------------------------------------------------------------------
__global__ __launch_bounds__(64) void build_wswz(
    const float* __restrict__ Wgx, const float* __restrict__ Wgh, const float* __restrict__ bg,
    const float* __restrict__ Wix, const float* __restrict__ Wih, const float* __restrict__ bi,
    const float* __restrict__ Wfx, const float* __restrict__ Wfh, const float* __restrict__ bf_,
    const float* __restrict__ Wox, const float* __restrict__ Woh, const float* __restrict__ bo,
    unsigned short* __restrict__ wswz, unsigned int* __restrict__ hxcz)
{
    {
        int4 z4 = {0, 0, 0, 0};
        size_t gid = (size_t)blockIdx.x * 64 + threadIdx.x;
        for (size_t i = gid; i < 131072; i += (size_t)NBLK_K1 * 64)
            ((int4*)hxcz)[i] = z4;
    }

    int g   = blockIdx.x / NKIT;   // ntile
    int kit = blockIdx.x % NKIT;
    int lane = threadIdx.x;
    int n = g * 16 + (lane & 15);
    int q = n >> 8;
    int col = n & 255;
    const float* Wh = (q == 0) ? Wgh : (q == 1) ? Wih : (q == 2) ? Wfh : Woh;
    const float* Wx = (q == 0) ? Wgx : (q == 1) ? Wix : (q == 2) ? Wfx : Wox;
    const float* bb = (q == 0) ? bg  : (q == 1) ? bi  : (q == 2) ? bf_ : bo;
    int k0 = kit * 32 + (lane >> 4) * 8;

    int4 out;
    unsigned short* p = (unsigned short*)&out;
#pragma unroll
    for (int jx = 0; jx < 8; jx++) {
        int k = k0 + jx;
        float v = 0.0f;
        if (k < 256)             v = Wh[k * 256 + col];
        else if (k < 256 + EMBD) v = Wx[(k - 256) * 256 + col];
        else if (k == 266)       v = bb[col];
        p[jx] = f2bf(v);
    }
    ((int4*)wswz)[(kit * 64 + g) * 64 + lane] = out;
}

// kit -> B source (compile-time s,g only; rule 20: no runtime indexing)
#define KIDX(s) ((s) == 7 ? 5 : (s))
#define BSRC(s, g) ((s) == 5 ? B_lds[(0 * 16 + (g) * 4 + j) * 64 + lane] \
                  : (s) == 6 ? B_lds[(1 * 16 + (g) * 4 + j) * 64 + lane] \
                  : breg[KIDX(s)][(g)])
#define DO_KIT(s) do { i32x4 a_ = Ahp[ah_rd + (s) * 4]; \
        acc0 = mfma_v(a_, BSRC(s, 0), acc0); \
        acc1 = mfma_v(a_, BSRC(s, 1), acc1); \
        acc2 = mfma_v(a_, BSRC(s, 2), acc2); \
        acc3 = mfma_v(a_, BSRC(s, 3), acc3); } while (0)

// ---------------------------------------------------------------------------
// K2: 4-way N-SPLIT persistent LSTM, WAVE-SPECIALIZED POLLER.
// 256 blocks x 320 threads: waves 0-3 = compute (R34's all-gates-per-wave,
// 36 MFMAs + in-register gates), wave 4 (tid 256-319) = poller.
// Per step interval the poller continuously polls the 3 remote quarters'
// seq-tagged u64s (12 dwordx4/thread = 12 KB), lands them into the
// PARITY-DOUBLE-BUFFERED Ah, then joins the single end-of-step barrier.
// Compute waves never stage/validate/spin: barrier -> kit8 -> kits 0..7 ->
// gate -> tail -> barrier. The exchange latency is absorbed by the poller
// during the producer's gate/tail window instead of stalling compute after
// the next barrier (R34's ~3.5k-cyc validate-retry segment).
// Safety: Ah[q] poller-lands (seq t+1) disjoint from Ah[p] compute reads
// (seq t); own-col tail writes to Ah[q] own region (disjoint cols from
// poller's remote region); hxc WAR by the R30 recurrence argument (one
// step looser, re-derived); ALL spins bounded (hang-proof).
// ---------------------------------------------------------------------------
__global__ __launch_bounds__(320)
void lstm_main(
    const int*   __restrict__ xtok,   // [1024][1][256]
    const float* __restrict__ emb,    // [32000][10]
    const float* __restrict__ Wph,    // [256][10]
    const float* __restrict__ bp,     // [10]
    const unsigned short* __restrict__ wswz,
    unsigned long long* __restrict__ hxc,  // [2][64][256 col][8 rowpair] u64
    float* __restrict__ out)          // [1024][10]
{
    __shared__ __align__(16) unsigned short A8_lds[2][64 * 8];   // 2 KB (kit 8: x+bias)
    __shared__ __align__(16) i32x4 B_lds[2 * 16 * 64];           // 32 KB (kits 5,6)
    __shared__ __align__(16) unsigned int Ah_lds[2][16 * 132];   // 16.9 KB (h, parity)
    __shared__ float hbuf[16][68];                               // 4.35 KB (epilogue)

    const int tid  = threadIdx.x;
    const int j    = tid >> 6;        // wave; compute: hcol ntile 0..3
    const int lane = tid & 63;
    const int qq   = lane >> 4;       // row quad 0..3
    const int col15 = lane & 15;
    const int blk  = blockIdx.x;
    const int gb   = blk & 63;        // batch group
    const int hg   = blk >> 6;        // hcol quarter 0..3
    const bool is_comp = (tid < 256);

    const int m_x = tid >> 4;         // x-gather row (compute only)
    const int e_x = tid & 15;

    const i32x4* Bg = (const i32x4*)wswz;

    // --- B prologue: regs for kits {0,1,2,3,4,7,8} x 4 gates (compute) ---
    i32x4 breg[7][4];
    if (is_comp) {
        const int ks[7] = {0, 1, 2, 3, 4, 7, 8};
#pragma unroll
        for (int i = 0; i < 7; i++)
#pragma unroll
            for (int g = 0; g < 4; g++)
                breg[i][g] = Bg[(ks[i] * 64 + g * 16 + hg * 4 + j) * 64 + lane];
    }
    // --- B LDS: kits 5,6 for this block's 16 ntiles (all threads) ---
    for (int i = tid; i < 2 * 16 * 64; i += 320) {
        int k   = i >> 10;          // 0->kit5, 1->kit6
        int ntl = (i >> 6) & 15;    // local ntile = g*4 + jj
        int ln  = i & 63;
        int g_ = ntl >> 2, jj = ntl & 3;
        B_lds[i] = Bg[((5 + k) * 64 + g_ * 16 + hg * 4 + jj) * 64 + ln];
    }

    // --- A8 init: zeros, bias (both parities), x_0 (parity 0) ---
    {
        int4 z4 = {0, 0, 0, 0};
        if (tid < 128) ((int4*)A8_lds)[tid] = z4;
    }
    __syncthreads();
    if (tid < 16) {
        A8_lds[0][(16 + tid) * 8 + 2] = 0x3F80;  // bias=1.0 at k-local=10
        A8_lds[1][(16 + tid) * 8 + 2] = 0x3F80;
    }
    if (is_comp && e_x < EMBD) {
        int tok = xtok[(gb * 16 + m_x) * T_STEPS + 0];
        float v = emb[tok * EMBD + e_x];
        A8_lds[0][(m_x + 16 * (e_x >> 3)) * 8 + (e_x & 7)] = f2bf(v);
    }
    __syncthreads();

    float c0 = 0.f, c1 = 0.f, c2 = 0.f, c3 = 0.f;

    // compute-path constants
    const int ah_rd = (lane & 15) * 33 + (lane >> 4);  // i32x4 units in Ah[p]
    const int c_own = hg * 64 + j * 16 + col15;

    // poller-path constants: 12 u64-pairs per poller thread
    const int ptid = tid - 256;
    int offv[12];
#pragma unroll
    for (int i = 0; i < 12; i++) {
        int e   = ptid * 24 + 2 * i;           // remote-u64 enumeration (even)
        int rqi = e >> 9;                      // 0..2
        offv[i] = (rqi + (rqi >= hg ? 1 : 0)) * 512 + (e & 511);
    }

    for (int t = 0; t < T_STEPS; t++) {
        const int p = t & 1, q = (t + 1) & 1;

        if (is_comp) {
            // x(t+1) prefetch (independent)
            float xval = 0.0f;
            const bool do_x = (t < T_STEPS - 1) && (e_x < EMBD);
            if (t < T_STEPS - 1) {
                int tok = xtok[(gb * 16 + m_x) * T_STEPS + (t + 1)];
                if (e_x < EMBD) xval = emb[tok * EMBD + e_x];
            }

            f32x4 acc0 = (f32x4){0.f, 0.f, 0.f, 0.f};
            f32x4 acc1 = (f32x4){0.f, 0.f, 0.f, 0.f};
            f32x4 acc2 = (f32x4){0.f, 0.f, 0.f, 0.f};
            f32x4 acc3 = (f32x4){0.f, 0.f, 0.f, 0.f};
            // kit 8 (x + bias)
            {
                i32x4 a8 = ((const i32x4*)A8_lds[p])[lane];
                acc0 = mfma_v(a8, breg[6][0], acc0);
                acc1 = mfma_v(a8, breg[6][1], acc1);
                acc2 = mfma_v(a8, breg[6][2], acc2);
                acc3 = mfma_v(a8, breg[6][3], acc3);
            }
            // kits 0..7: entire h(t) already in Ah[p] (poller landed remote
            // during interval t-1; own written at our tail(t-1))
            if (t > 0) {
                const i32x4* Ahp = (const i32x4*)Ah_lds[p];
                DO_KIT(0); DO_KIT(1); DO_KIT(2); DO_KIT(3);
                DO_KIT(4); DO_KIT(5); DO_KIT(6); DO_KIT(7);
            }

            // gate math fully in registers (rows qq*4+r, col c_own)
            float h0, h1, h2, h3;
            {
                float gg, ii, ff, oo, cn;
                gg = tanh_fast(acc0[0]); ii = sig_fast(acc1[0]);
                ff = sig_fast(acc2[0]);  oo = sig_fast(acc3[0]);
                cn = gg * ii + c0 * ff; c0 = cn; h0 = tanh_fast(cn) * oo;
                gg = tanh_fast(acc0[1]); ii = sig_fast(acc1[1]);
                ff = sig_fast(acc2[1]);  oo = sig_fast(acc3[1]);
                cn = gg * ii + c1 * ff; c1 = cn; h1 = tanh_fast(cn) * oo;
                gg = tanh_fast(acc0[2]); ii = sig_fast(acc1[2]);
                ff = sig_fast(acc2[2]);  oo = sig_fast(acc3[2]);
                cn = gg * ii + c2 * ff; c2 = cn; h2 = tanh_fast(cn) * oo;
                gg = tanh_fast(acc0[3]); ii = sig_fast(acc1[3]);
                ff = sig_fast(acc2[3]);  oo = sig_fast(acc3[3]);
                cn = gg * ii + c3 * ff; c3 = cn; h3 = tanh_fast(cn) * oo;
            }

            if (t < T_STEPS - 1) {
                unsigned int p01, p23;
                asm("v_cvt_pk_bf16_f32 %0, %1, %2" : "=v"(p01) : "v"(h0), "v"(h1));
                asm("v_cvt_pk_bf16_f32 %0, %1, %2" : "=v"(p23) : "v"(h2), "v"(h3));
                // own col -> Ah[q] own region (read by us after next barrier)
                unsigned short* AqS = (unsigned short*)Ah_lds[q];
                AqS[(4 * qq + 0) * 264 + c_own] = (unsigned short)(p01 & 0xffff);
                AqS[(4 * qq + 1) * 264 + c_own] = (unsigned short)(p01 >> 16);
                AqS[(4 * qq + 2) * 264 + c_own] = (unsigned short)(p23 & 0xffff);
                AqS[(4 * qq + 3) * 264 + c_own] = (unsigned short)(p23 >> 16);
                if (do_x)
                    A8_lds[q][(m_x + 16 * (e_x >> 3)) * 8 + (e_x & 7)] = f2bf(xval);
                // fire-and-forget: ONE dwordx4 = 2 tagged u64 (rowpairs 2q,2q+1)
                i32x4 pv;
                pv.x = (int)p01; pv.y = t + 1; pv.z = (int)p23; pv.w = t + 1;
                unsigned long long* dst =
                    hxc + (size_t)(q * 64 + gb) * 2048 + (size_t)c_own * 8 + 2 * qq;
                asm volatile("global_store_dwordx4 %0, %1, off sc1"
                             :: "v"(dst), "v"(pv) : "memory");
            } else {
                // stash final h for epilogue
                hbuf[4 * qq + 0][j * 16 + col15] = h0;
                hbuf[4 * qq + 1][j * 16 + col15] = h1;
                hbuf[4 * qq + 2][j * 16 + col15] = h2;
                hbuf[4 * qq + 3][j * 16 + col15] = h3;
            }
        } else {
            // ---------------- POLLER (wave 4) ----------------
            if (t < T_STEPS - 1) {
                const unsigned long long* hbq =
                    hxc + (size_t)(q * 64 + gb) * 2048;
                const unsigned s_exp = (unsigned)(t + 1);
                i32x4 pv[12];
                int spins = 0;
                for (;;) {
#pragma unroll
                    for (int i = 0; i < 12; i++)
                        asm volatile("global_load_dwordx4 %0, %1, off sc1"
                                     : "=&v"(pv[i]) : "v"(hbq + offv[i]) : "memory");
                    asm volatile("s_waitcnt vmcnt(0)"
                                 : "+v"(pv[0]), "+v"(pv[1]), "+v"(pv[2]), "+v"(pv[3]),
                                   "+v"(pv[4]), "+v"(pv[5]), "+v"(pv[6]), "+v"(pv[7]),
                                   "+v"(pv[8]), "+v"(pv[9]), "+v"(pv[10]), "+v"(pv[11])
                                 :: "memory");
                    unsigned bad = 0;
#pragma unroll
                    for (int i = 0; i < 12; i++)
                        bad |= ((unsigned)pv[i].y ^ s_exp) | ((unsigned)pv[i].w ^ s_exp);
                    if (!bad || spins >= 20000) break;
                    ++spins;
                    __builtin_amdgcn_s_sleep(1);
                }
                // transpose-land into Ah[q] remote region
                unsigned short* AqS = (unsigned short*)Ah_lds[q];
#pragma unroll
                for (int i = 0; i < 12; i++) {
                    const int cg = offv[i] >> 3;
                    const int r0 = (offv[i] & 7) * 2;
                    AqS[(r0 + 0) * 264 + cg] = (unsigned short)(pv[i].x & 0xffff);
                    AqS[(r0 + 1) * 264 + cg] = (unsigned short)((unsigned)pv[i].x >> 16);
                    AqS[(r0 + 2) * 264 + cg] = (unsigned short)(pv[i].z & 0xffff);
                    AqS[(r0 + 3) * 264 + cg] = (unsigned short)((unsigned)pv[i].z >> 16);
                }
            }
        }

        if (t < T_STEPS - 1) {
            // single end-of-step barrier: drains all LDS writes (tails + lands)
            asm volatile("s_waitcnt lgkmcnt(0)" ::: "memory");
            __builtin_amdgcn_s_barrier();
        }
    }

    // --- epilogue: project final h from hbuf ---
    __syncthreads();
    if (tid < 160) {
        int m = tid / 10, cl = tid - m * 10;
        float s = 0.0f;
#pragma unroll 8
        for (int c = 0; c < 64; c++)
            s += hbuf[m][c] * Wph[(hg * 64 + c) * 10 + cl];
        if (hg == 0) s += bp[cl];     // bias added exactly once per row
        atomicAdd(&out[(gb * 16 + m) * 10 + cl], s);
    }
}

extern "C" void kernel_launch(void* const* d_in, const int* in_sizes, int n_in,
                              void* d_out, int out_size, void* d_ws, size_t ws_size,
                              hipStream_t stream) {
    const int*   x    = (const int*)  d_in[0];
    const float* emb  = (const float*)d_in[1];
    const float* Wgx  = (const float*)d_in[2];
    const float* Wgh  = (const float*)d_in[3];
    const float* bg   = (const float*)d_in[4];
    const float* Wix  = (const float*)d_in[5];
    const float* Wih  = (const float*)d_in[6];
    const float* bi   = (const float*)d_in[7];
    const float* Wfx  = (const float*)d_in[8];
    const float* Wfh  = (const float*)d_in[9];
    const float* bf_  = (const float*)d_in[10];
    const float* Wox  = (const float*)d_in[11];
    const float* Woh  = (const float*)d_in[12];
    const float* bo   = (const float*)d_in[13];
    const float* Wph  = (const float*)d_in[14];
    const float* bp   = (const float*)d_in[15];

    char* ws = (char*)d_ws;
    unsigned short*     wswz = (unsigned short*)ws;                 // 576 KB
    unsigned long long* hxc  = (unsigned long long*)(ws + 589824 + 4096); // 2 MB

    build_wswz<<<NBLK_K1, 64, 0, stream>>>(Wgx, Wgh, bg, Wix, Wih, bi,
                                           Wfx, Wfh, bf_, Wox, Woh, bo,
                                           wswz, (unsigned int*)hxc);
    lstm_main<<<NBLK, 320, 0, stream>>>(x, emb, Wph, bp, wswz, hxc,
                                        (float*)d_out);
}

// Round 20
// 532.004 us; speedup vs baseline: 2.5332x; 2.5332x over previous
//
#include <hip/hip_runtime.h>
#include <stdint.h>

#define T_STEPS 256
#define EMBD 10
#define NKIT 9          // K = 288 = 9*32 (256 h + 10 x + 1 bias + pad)
#define NBLK_K1 (64 * NKIT)
#define NBLK 256        // main grid: 4 hcol-quarters x 64 batch-groups

typedef __attribute__((ext_vector_type(8))) short bf16x8;
typedef __attribute__((ext_vector_type(4))) float f32x4;
typedef __attribute__((ext_vector_type(4))) int   i32x4;

__device__ __forceinline__ unsigned short f2bf(float f) {
    union { float f; unsigned int u; } v; v.f = f;
    unsigned int u = v.u;
    unsigned int r = (u + 0x7FFFu + ((u >> 16) & 1u)) >> 16;  // RNE
    return (unsigned short)r;
}
__device__ __forceinline__ float sig_fast(float x) {
    return __builtin_amdgcn_rcpf(1.0f + __builtin_amdgcn_exp2f(-1.4426950408889634f * x));
}
__device__ __forceinline__ float tanh_fast(float x) {
    return 1.0f - 2.0f * __builtin_amdgcn_rcpf(__builtin_amdgcn_exp2f(2.8853900817779268f * x) + 1.0f);
}
__device__ __forceinline__ f32x4 mfma_v(i32x4 a, i32x4 b, f32x4 c) {
    return __builtin_amdgcn_mfma_f32_16x16x32_bf16(
        __builtin_bit_cast(bf16x8, a), __builtin_bit_cast(bf16x8, b), c, 0, 0, 0);
}

// ---------------------------------------------------------------------------
// K1: swizzled bf16 weights [kit][ntile][lane] x 16B + zero the 2 MB hxc
// (seq words must start != any expected step; zero works, expected >= 1).
// ---------------------------------------------------------------------------
__global__ __launch_bounds__(64) void build_wswz(
    const float* __restrict__ Wgx, const float* __restrict__ Wgh, const float* __restrict__ bg,
    const float* __restrict__ Wix, const float* __restrict__ Wih, const float* __restrict__ bi,
    const float* __restrict__ Wfx, const float* __restrict__ Wfh, const float* __restrict__ bf_,
    const float* __restrict__ Wox, const float* __restrict__ Woh, const float* __restrict__ bo,
    unsigned short* __restrict__ wswz, unsigned int* __restrict__ hxcz)
{
    {
        int4 z4 = {0, 0, 0, 0};
        size_t gid = (size_t)blockIdx.x * 64 + threadIdx.x;
        for (size_t i = gid; i < 131072; i += (size_t)NBLK_K1 * 64)
            ((int4*)hxcz)[i] = z4;
    }

    int g   = blockIdx.x / NKIT;   // ntile
    int kit = blockIdx.x % NKIT;
    int lane = threadIdx.x;
    int n = g * 16 + (lane & 15);
    int q = n >> 8;
    int col = n & 255;
    const float* Wh = (q == 0) ? Wgh : (q == 1) ? Wih : (q == 2) ? Wfh : Woh;
    const float* Wx = (q == 0) ? Wgx : (q == 1) ? Wix : (q == 2) ? Wfx : Wox;
    const float* bb = (q == 0) ? bg  : (q == 1) ? bi  : (q == 2) ? bf_ : bo;
    int k0 = kit * 32 + (lane >> 4) * 8;

    int4 out;
    unsigned short* p = (unsigned short*)&out;
#pragma unroll
    for (int jx = 0; jx < 8; jx++) {
        int k = k0 + jx;
        float v = 0.0f;
        if (k < 256)             v = Wh[k * 256 + col];
        else if (k < 256 + EMBD) v = Wx[(k - 256) * 256 + col];
        else if (k == 266)       v = bb[col];
        p[jx] = f2bf(v);
    }
    ((int4*)wswz)[(kit * 64 + g) * 64 + lane] = out;
}

// kit -> B source (compile-time s only; rule 20: no runtime indexing)
#define KIDX(s) ((s) == 7 ? 5 : (s))
#define BSRC2(s, jj) ((s) == 5 ? B_lds[(0 * 16 + gate * 4 + ntl0 + (jj)) * 64 + lane] \
                    : (s) == 6 ? B_lds[(1 * 16 + gate * 4 + ntl0 + (jj)) * 64 + lane] \
                    : breg[KIDX(s)][(jj)])
#define DO_KIT(s) do { i32x4 a_ = ((const i32x4*)Ah_lds)[ah_rd + (s) * 4]; \
        acc0 = mfma_v(a_, BSRC2(s, 0), acc0); \
        acc1 = mfma_v(a_, BSRC2(s, 1), acc1); } while (0)

// ---------------------------------------------------------------------------
// K2: R37 = R31 TRULY VERBATIM (session best: 470us dispatch, passed).
// R36's NaN was a transcription bug: the producer hxc offset and own-tail
// Ah_lds offset used hg*16 (R32's eighth stride) instead of R31's hg*32
// (quarter = 64 hcols = 32 u64/row). Both restored here; nothing else
// differs. Structure: 4-way N-split, 256 blocks x 512 threads, 1/CU.
// Exchange: self-validating seq-tagged u64 {hi:seq, lo:2xbf16}, sc1
// fire-and-forget stores, combined-reload retry, compute-under-RT,
// raw s_barriers with lgkmcnt-only waits, bounded spins.
// ---------------------------------------------------------------------------
__global__ __launch_bounds__(512, 4)
void lstm_main(
    const int*   __restrict__ xtok,   // [1024][1][256]
    const float* __restrict__ emb,    // [32000][10]
    const float* __restrict__ Wph,    // [256][10]
    const float* __restrict__ bp,     // [10]
    const unsigned short* __restrict__ wswz,
    unsigned long long* __restrict__ hxc,  // [2][64][16][128] u64 {seq, 2xbf16}
    float* __restrict__ out)          // [1024][10]
{
    __shared__ __align__(16) unsigned short A8_lds[2][64 * 8];  // 2 KB (kit 8: x+bias)
    __shared__ __align__(16) i32x4 B_lds[2 * 16 * 64];          // 32 KB (kits 5,6)
    __shared__ __align__(16) unsigned int Ah_lds[16 * 132];     // 8.25 KB (h, padded)
    __shared__ float z_lds[4 * 16 * 66];                        // 16.5 KB (padded 66)
    __shared__ float outacc[160];

    const int tid  = threadIdx.x;
    const int w    = tid >> 6;        // wave 0..7
    const int lane = tid & 63;
    const int blk  = blockIdx.x;
    const int gb   = blk & 63;        // batch group
    const int hg   = blk >> 6;        // hcol quarter 0..3

    const int gate = w & 3;
    const int ntl0 = (w >> 2) * 2;    // local h-ntile pair base (0 or 2)

    const int m_x = tid >> 4;         // x-gather row (tid<256)
    const int e_x = tid & 15;

    const int r_gm = tid >> 5;        // gate-math row 0..15
    const int hc0  = (tid * 2) & 63;  // gate-math col pair base (even)

    const i32x4* Bg = (const i32x4*)wswz;

    // --- B prologue: regs for kits {0,1,2,3,4,7,8} (56 VGPRs) ---
    i32x4 breg[7][2];
    {
        const int ks[7] = {0, 1, 2, 3, 4, 7, 8};
#pragma unroll
        for (int i = 0; i < 7; i++)
#pragma unroll
            for (int jj = 0; jj < 2; jj++) {
                int ntile = gate * 16 + hg * 4 + ntl0 + jj;
                breg[i][jj] = Bg[(ks[i] * 64 + ntile) * 64 + lane];
            }
    }
    // --- B LDS: kits 5,6 for this block's 16 ntiles ---
    for (int i = tid; i < 2 * 16 * 64; i += 512) {
        int k   = i >> 10;          // 0->kit5, 1->kit6
        int ntl = (i >> 6) & 15;    // local ntile = gt*4 + jx
        int ln  = i & 63;
        int gt = ntl >> 2, jx = ntl & 3;
        B_lds[i] = Bg[((5 + k) * 64 + gt * 16 + hg * 4 + jx) * 64 + ln];
    }

    // --- A8 init: zeros, bias (both parities), x_0 (parity 0) ---
    {
        int4 z4 = {0, 0, 0, 0};
        if (tid < 128) ((int4*)A8_lds)[tid] = z4;
    }
    __syncthreads();
    if (tid < 16) {
        A8_lds[0][(16 + tid) * 8 + 2] = 0x3F80;  // bias=1.0 at k-local=10
        A8_lds[1][(16 + tid) * 8 + 2] = 0x3F80;
    }
    if (tid < 256 && e_x < EMBD) {
        int tok = xtok[(gb * 16 + m_x) * T_STEPS + 0];
        float v = emb[tok * EMBD + e_x];
        A8_lds[0][(m_x + 16 * (e_x >> 3)) * 8 + (e_x & 7)] = f2bf(v);
    }
    __syncthreads();

    float c0 = 0.0f, c1 = 0.0f;

    // af LDS read base (i32x4 units): row (lane&15)*33 + quad; kit s at +4s
    const int ah_rd = (lane & 15) * 33 + (lane >> 4);
    // per-thread exchange slot: row (tid>>5), pair (tid&31)
    const int s_row  = tid >> 5;
    const int s_pair = tid & 31;
    const int rq0 = (hg + 1) & 3, rq1 = (hg + 2) & 3, rq2 = (hg + 3) & 3;

    for (int t = 0; t < T_STEPS; t++) {
        const int p = t & 1, q = (t + 1) & 1;

        // x(t+1) prefetch (independent)
        float xval = 0.0f;
        const bool do_x = (t < T_STEPS - 1) && (tid < 256) && (e_x < EMBD);
        if ((t < T_STEPS - 1) && (tid < 256)) {
            int tok = xtok[(gb * 16 + m_x) * T_STEPS + (t + 1)];
            if (e_x < EMBD) xval = emb[tok * EMBD + e_x];
        }

        const unsigned long long* hb = hxc + (size_t)(p * 64 + gb) * 2048;
        const unsigned long long* a0 = hb + s_row * 128 + rq0 * 32 + s_pair;
        const unsigned long long* a1 = hb + s_row * 128 + rq1 * 32 + s_pair;
        const unsigned long long* a2 = hb + s_row * 128 + rq2 * 32 + s_pair;
        unsigned long long v0 = 0, v1 = 0, v2 = 0;

        // ISSUE remote h(t) loads -- no wait, stays in flight across barrier
        if (t > 0) {
            asm volatile("global_load_dwordx2 %0, %3, off sc1\n\t"
                         "global_load_dwordx2 %1, %4, off sc1\n\t"
                         "global_load_dwordx2 %2, %5, off sc1"
                         : "=&v"(v0), "=&v"(v1), "=&v"(v2)
                         : "v"(a0), "v"(a1), "v"(a2) : "memory");
        }

        // LAND-own: raw barrier, LDS-only wait (keeps vmem in flight)
        asm volatile("s_waitcnt lgkmcnt(0)" ::: "memory");
        __builtin_amdgcn_s_barrier();

        f32x4 acc0 = (f32x4){0.f, 0.f, 0.f, 0.f};
        f32x4 acc1 = (f32x4){0.f, 0.f, 0.f, 0.f};
        // kit 8 (x + bias) -- h-independent
        {
            i32x4 a8 = ((const i32x4*)A8_lds[p])[lane];
            acc0 = mfma_v(a8, breg[6][0], acc0);
            acc1 = mfma_v(a8, breg[6][1], acc1);
        }

        if (t > 0) {
            // own-quarter kits (h in LDS from our own tail write) under the RT
            if      (hg == 0) { DO_KIT(0); DO_KIT(1); }
            else if (hg == 1) { DO_KIT(2); DO_KIT(3); }
            else if (hg == 2) { DO_KIT(4); DO_KIT(5); }
            else              { DO_KIT(6); DO_KIT(7); }

            // validate: wait threaded through v0..v2 (orders the reg reads)
            asm volatile("s_waitcnt vmcnt(0)"
                         : "+v"(v0), "+v"(v1), "+v"(v2) :: "memory");
            int spins = 0;
            while (((unsigned)(v0 >> 32) != (unsigned)t ||
                    (unsigned)(v1 >> 32) != (unsigned)t ||
                    (unsigned)(v2 >> 32) != (unsigned)t) && spins < 200000) {
                ++spins;
                __builtin_amdgcn_s_sleep(1);
                // reload ALL THREE in one block: overlapped RTs
                asm volatile("global_load_dwordx2 %0, %3, off sc1\n\t"
                             "global_load_dwordx2 %1, %4, off sc1\n\t"
                             "global_load_dwordx2 %2, %5, off sc1\n\t"
                             "s_waitcnt vmcnt(0)"
                             : "=&v"(v0), "=&v"(v1), "=&v"(v2)
                             : "v"(a0), "v"(a1), "v"(a2) : "memory");
            }
            Ah_lds[s_row * 132 + rq0 * 32 + s_pair] = (unsigned int)v0;
            Ah_lds[s_row * 132 + rq1 * 32 + s_pair] = (unsigned int)v1;
            Ah_lds[s_row * 132 + rq2 * 32 + s_pair] = (unsigned int)v2;

            // LAND-remote: raw barrier, LDS-only wait
            asm volatile("s_waitcnt lgkmcnt(0)" ::: "memory");
            __builtin_amdgcn_s_barrier();

            // 6 remote kits
            if (hg != 0) { DO_KIT(0); DO_KIT(1); }
            if (hg != 1) { DO_KIT(2); DO_KIT(3); }
            if (hg != 2) { DO_KIT(4); DO_KIT(5); }
            if (hg != 3) { DO_KIT(6); DO_KIT(7); }
        }

        // z -> z_lds (C layout: batch row m = (lane>>4)*4+reg, ncol = lane&15)
        {
            const int col = lane & 15, qd = lane >> 4;
#pragma unroll
            for (int rr = 0; rr < 4; rr++) {
                z_lds[(gate * 16 + qd * 4 + rr) * 66 + (ntl0 + 0) * 16 + col] = acc0[rr];
                z_lds[(gate * 16 + qd * 4 + rr) * 66 + (ntl0 + 1) * 16 + col] = acc1[rr];
            }
        }
        __syncthreads();  // B1: z complete (af reads also retired)

        // gate math: 2 h-values per thread (row r_gm, hcols hc0/hc0+1)
        float zg[4], zh[4];
#pragma unroll
        for (int g = 0; g < 4; g++) {
            const float2 zz = *(const float2*)&z_lds[(g * 16 + r_gm) * 66 + hc0];
            zg[g] = zz.x; zh[g] = zz.y;
        }
        float hh0, hh1;
        {
            float gg = tanh_fast(zg[0]), ii = sig_fast(zg[1]);
            float ff = sig_fast(zg[2]),  oo = sig_fast(zg[3]);
            float cn = gg * ii + c0 * ff; c0 = cn;
            hh0 = tanh_fast(cn) * oo;
        }
        {
            float gg = tanh_fast(zh[0]), ii = sig_fast(zh[1]);
            float ff = sig_fast(zh[2]),  oo = sig_fast(zh[3]);
            float cn = gg * ii + c1 * ff; c1 = cn;
            hh1 = tanh_fast(cn) * oo;
        }

        if (t < T_STEPS - 1) {
            unsigned int hp;
            asm("v_cvt_pk_bf16_f32 %0, %1, %2" : "=v"(hp) : "v"(hh0), "v"(hh1));
            // own quarter straight to LDS (consumed after next LAND-own)
            Ah_lds[r_gm * 132 + hg * 32 + (hc0 >> 1)] = hp;
            if (do_x)
                A8_lds[q][(m_x + 16 * (e_x >> 3)) * 8 + (e_x & 7)] = f2bf(xval);
            // fire-and-forget seq-tagged u64 (no drain, no flag)
            unsigned long long pv =
                ((unsigned long long)(unsigned int)(t + 1) << 32) | (unsigned long long)hp;
            unsigned long long* dst =
                hxc + (size_t)(q * 64 + gb) * 2048 + r_gm * 128 + hg * 32 + (hc0 >> 1);
            asm volatile("global_store_dwordx2 %0, %1, off sc1"
                         :: "v"(dst), "v"(pv) : "memory");
        } else {
            // --- epilogue: project final h (held in hh0/hh1) ---
            if (tid < 160) outacc[tid] = 0.0f;
            __syncthreads();
            const int hcg = hg * 64 + hc0;
            float part[10];
#pragma unroll
            for (int cl = 0; cl < 10; cl++)
                part[cl] = hh0 * Wph[hcg * 10 + cl] + hh1 * Wph[(hcg + 1) * 10 + cl];
#pragma unroll
            for (int cl = 0; cl < 10; cl++)
                atomicAdd(&outacc[r_gm * 10 + cl], part[cl]);
            __syncthreads();
            if (tid < 160) {
                int m = tid / 10, cl = tid - m * 10;
                float v = outacc[tid];
                if (hg == 0) v += bp[cl];     // bias added exactly once per row
                atomicAdd(&out[(gb * 16 + m) * 10 + cl], v);
            }
        }
    }
}

extern "C" void kernel_launch(void* const* d_in, const int* in_sizes, int n_in,
                              void* d_out, int out_size, void* d_ws, size_t ws_size,
                              hipStream_t stream) {
    const int*   x    = (const int*)  d_in[0];
    const float* emb  = (const float*)d_in[1];
    const float* Wgx  = (const float*)d_in[2];
    const float* Wgh  = (const float*)d_in[3];
    const float* bg   = (const float*)d_in[4];
    const float* Wix  = (const float*)d_in[5];
    const float* Wih  = (const float*)d_in[6];
    const float* bi   = (const float*)d_in[7];
    const float* Wfx  = (const float*)d_in[8];
    const float* Wfh  = (const float*)d_in[9];
    const float* bf_  = (const float*)d_in[10];
    const float* Wox  = (const float*)d_in[11];
    const float* Woh  = (const float*)d_in[12];
    const float* bo   = (const float*)d_in[13];
    const float* Wph  = (const float*)d_in[14];
    const float* bp   = (const float*)d_in[15];

    char* ws = (char*)d_ws;
    unsigned short*     wswz = (unsigned short*)ws;                 // 576 KB
    unsigned long long* hxc  = (unsigned long long*)(ws + 589824 + 4096); // 2 MB

    build_wswz<<<NBLK_K1, 64, 0, stream>>>(Wgx, Wgh, bg, Wix, Wih, bi,
                                           Wfx, Wfh, bf_, Wox, Woh, bo,
                                           wswz, (unsigned int*)hxc);
    lstm_main<<<NBLK, 512, 0, stream>>>(x, emb, Wph, bp, wswz, hxc,
                                        (float*)d_out);
}